// Round 13
// baseline (91.690 us; speedup 1.0000x reference)
//
#include <hip/hip_runtime.h>
#include <math.h>

#define NPTS 512
#define DIM  768
#define KNN  64
#define NH   8
#define HDIM 96
#define MROWS 1024   // B*NP
#define MPAD  1088   // MROWS + 2 (Wd,bd rows) padded to 64
#define WOROWS 832   // 768 Wo rows + 1 bo row, padded to 64
#define WSQ   ((size_t)DIM * DIM)

typedef unsigned short u16;
typedef unsigned long long ull;
typedef __attribute__((ext_vector_type(8))) short short8;
typedef __attribute__((ext_vector_type(4))) float f32x4;

__device__ __forceinline__ unsigned f2bf(float f) {
    unsigned u = __float_as_uint(f);
    return (u + 0x7fffu + ((u >> 16) & 1u)) >> 16;   // round-to-nearest-even
}
__device__ __forceinline__ float bf2f(u16 v) {
    return __uint_as_float(((unsigned)v) << 16);
}

// ---------------------------------------------------------------------------
// Prep kernel (pure converts): one launch.
//  [0,768)     : features fp32 -> bf16 (Fb rows 0..1023)
//  [768,816)   : Fb rows 1024(Wd) 1025(bd) 1026..1087(zero)
//  [816,1440)  : Wob = bf16([Wo; bo; 0...])  (832x768)
//  [1440,2160) : 5 transposes fp32[k][n] -> bf16 [n][k]: Wq,Wk,Wv,WeTop,WeBot
// ---------------------------------------------------------------------------
__global__ __launch_bounds__(256) void mega_prep_k(
    const float* __restrict__ features,
    const float* __restrict__ Wd, const float* __restrict__ bd,
    const float* __restrict__ Wq, const float* __restrict__ Wk, const float* __restrict__ Wv,
    const float* __restrict__ Wo, const float* __restrict__ bo, const float* __restrict__ We,
    u16* __restrict__ Fb, u16* __restrict__ Wob, u16* __restrict__ W3)
{
    __shared__ float T[64][65];
    int bid = blockIdx.x, tid = threadIdx.x;

    if (bid < 768) {                       // ---- convF
        int i = (bid * 256 + tid) * 4;
        float4 v = *(const float4*)&features[i];
        uint2 o;
        o.x = f2bf(v.x) | (f2bf(v.y) << 16);
        o.y = f2bf(v.z) | (f2bf(v.w) << 16);
        *(uint2*)&Fb[i] = o;
        return;
    }
    if (bid < 816) {                       // ---- extra A rows
        int flat = (bid - 768) * 1024 + tid * 4;   // 64x768 region
        int r = flat / DIM, c = flat - r * DIM;
        uint2 o; o.x = 0u; o.y = 0u;
        if (r == 0) {
            float4 v = *(const float4*)&Wd[c];
            o.x = f2bf(v.x) | (f2bf(v.y) << 16);
            o.y = f2bf(v.z) | (f2bf(v.w) << 16);
        } else if (r == 1) {
            float4 v = *(const float4*)&bd[c];
            o.x = f2bf(v.x) | (f2bf(v.y) << 16);
            o.y = f2bf(v.z) | (f2bf(v.w) << 16);
        }
        *(uint2*)&Fb[(size_t)(MROWS + r) * DIM + c] = o;
        return;
    }
    if (bid < 1440) {                      // ---- Wob = [Wo; bo; zeros]
        int flat = (bid - 816) * 1024 + tid * 4;   // 832x768 region
        int r = flat / DIM, c = flat - r * DIM;
        uint2 o; o.x = 0u; o.y = 0u;
        if (r < DIM) {
            float4 v = *(const float4*)&Wo[(size_t)r * DIM + c];
            o.x = f2bf(v.x) | (f2bf(v.y) << 16);
            o.y = f2bf(v.z) | (f2bf(v.w) << 16);
        } else if (r == DIM) {
            float4 v = *(const float4*)&bo[c];
            o.x = f2bf(v.x) | (f2bf(v.y) << 16);
            o.y = f2bf(v.z) | (f2bf(v.w) << 16);
        }
        *(uint2*)&Wob[(size_t)r * DIM + c] = o;
        return;
    }
    // ---- convT: 5 matrices x 144 (12x12) tile-blocks
    {
        int t = bid - 1440;
        int m = t / 144, r2 = t % 144;
        int by = r2 / 12, bx = r2 % 12;
        const float* S = (m == 0) ? Wq : (m == 1) ? Wk : (m == 2) ? Wv
                       : (m == 3) ? We : (We + WSQ);
        u16* D = W3 + (size_t)m * WSQ;
        int r0 = by * 64, c0 = bx * 64;
#pragma unroll
        for (int i = 0; i < 16; ++i) {
            int lin = tid + i * 256;
            int r = lin >> 6, c = lin & 63;
            T[r][c] = S[(size_t)(r0 + r) * DIM + c0 + c];
        }
        __syncthreads();
#pragma unroll
        for (int i = 0; i < 16; ++i) {
            int lin = tid + i * 256;
            int c = lin >> 6, r = lin & 63;
            D[(size_t)(c0 + c) * DIM + r0 + r] = (u16)f2bf(T[r][c]);
        }
    }
}

// ---------------------------------------------------------------------------
// Standalone topk: per-point pairwise distance + top-64, LDS bitonic sort
// (R9's best-measured variant). grid 1024, 256 threads.
// ---------------------------------------------------------------------------
__global__ __launch_bounds__(256) void topk_k(
    const float* __restrict__ pts, int* __restrict__ idxb, float* __restrict__ distb)
{
    __shared__ float P[NPTS * 3];
    __shared__ ull keys[NPTS];
    int bn = blockIdx.x, tid = threadIdx.x;
    int b  = bn >> 9;
    int n  = bn & (NPTS - 1);
    const float* pb = pts + (size_t)b * NPTS * 3;
    for (int i = tid; i < NPTS * 3; i += 256) P[i] = pb[i];
    __syncthreads();
    float xn = P[n * 3], yn = P[n * 3 + 1], zn = P[n * 3 + 2];
    float sqn = xn * xn + yn * yn + zn * zn;
    for (int m = tid; m < NPTS; m += 256) {
        float xm = P[m * 3], ym = P[m * 3 + 1], zm = P[m * 3 + 2];
        float sqm = xm * xm + ym * ym + zm * zm;
        float d2 = sqn + sqm - 2.0f * (xn * xm + yn * ym + zn * zm);
        float dist = sqrtf(fmaxf(d2, 0.0f));
        keys[m] = (((ull)__float_as_uint(dist)) << 32) | (unsigned)m;
    }
    __syncthreads();
    for (int k = 2; k <= NPTS; k <<= 1) {
        for (int j = k >> 1; j > 0; j >>= 1) {
            for (int i = tid; i < NPTS; i += 256) {
                int ixj = i ^ j;
                if (ixj > i) {
                    bool asc = ((i & k) == 0);
                    ull a = keys[i], bb = keys[ixj];
                    if ((a > bb) == asc) { keys[i] = bb; keys[ixj] = a; }
                }
            }
            __syncthreads();
        }
    }
    if (tid < KNN) {
        ull kk = keys[tid];
        idxb[(size_t)bn * KNN + tid]  = (int)(kk & 0xffffffffu);
        distb[(size_t)bn * KNN + tid] = __uint_as_float((unsigned)(kk >> 32));
    }
}

// ---------------------------------------------------------------------------
// Standalone 5-slice GEMM (R11's 64-tile structure). grid 1008 flat:
//  bid < 816   : z = bid/204 (z0:FQ z1:FKb z2:FVb z3:WeffT+c_e)
//  [816,1008)  : z4: Z0 = Fb @ WeTopT + be
// ---------------------------------------------------------------------------
__global__ __launch_bounds__(256) void gemm5_k(
    const u16* __restrict__ Fb, const u16* __restrict__ Wob, const u16* __restrict__ W3,
    const float* __restrict__ bq, const float* __restrict__ be,
    float* __restrict__ FQ, u16* __restrict__ FKb, u16* __restrict__ FVb,
    u16* __restrict__ WeffT, float* __restrict__ c_e, float* __restrict__ Z0)
{
    __shared__ short As[64][72];
    __shared__ short Bs[64][72];
    int bid = blockIdx.x, tid = threadIdx.x;

    int z, by, bx;
    if (bid < 816) {
        z = bid / 204;
        int rem = bid - z * 204;
        by = rem / 12; bx = rem - by * 12;
        if (z == 0 && by >= 16) return;
        if (z == 3 && by >= 13) return;
    } else {
        z = 4;
        int rem = bid - 816;
        by = rem / 12; bx = rem - by * 12;
    }
    const u16* A  = (z == 3) ? Wob : Fb;
    const u16* BT = W3 + (size_t)((z == 3) ? 4 : (z == 4) ? 3 : z) * WSQ;

    int wave = tid >> 6, lane = tid & 63;
    int wr = (wave >> 1) * 32, wc = (wave & 1) * 32;
    int l15 = lane & 15, kg = lane >> 4;
    int brow = by * 64, bcol = bx * 64;

    f32x4 acc[2][2] = {};

    int srow = tid >> 3;            // 0..31
    int scol = (tid & 7) * 8;       // 0,8,..,56

    for (int k0 = 0; k0 < DIM; k0 += 64) {
#pragma unroll
        for (int s = 0; s < 2; ++s) {
            int r = srow + s * 32;
            *(short8*)&As[r][scol] = *(const short8*)&A[(size_t)(brow + r) * DIM + k0 + scol];
            *(short8*)&Bs[r][scol] = *(const short8*)&BT[(size_t)(bcol + r) * DIM + k0 + scol];
        }
        __syncthreads();
#pragma unroll
        for (int kk = 0; kk < 2; ++kk) {
            short8 a0 = *(const short8*)&As[wr + l15][kk * 32 + kg * 8];
            short8 a1 = *(const short8*)&As[wr + 16 + l15][kk * 32 + kg * 8];
            short8 b0 = *(const short8*)&Bs[wc + l15][kk * 32 + kg * 8];
            short8 b1 = *(const short8*)&Bs[wc + 16 + l15][kk * 32 + kg * 8];
            acc[0][0] = __builtin_amdgcn_mfma_f32_16x16x32_bf16(a0, b0, acc[0][0], 0, 0, 0);
            acc[0][1] = __builtin_amdgcn_mfma_f32_16x16x32_bf16(a0, b1, acc[0][1], 0, 0, 0);
            acc[1][0] = __builtin_amdgcn_mfma_f32_16x16x32_bf16(a1, b0, acc[1][0], 0, 0, 0);
            acc[1][1] = __builtin_amdgcn_mfma_f32_16x16x32_bf16(a1, b1, acc[1][1], 0, 0, 0);
        }
        __syncthreads();
    }

    // D layout: col = lane&15, row = (lane>>4)*4 + j
#pragma unroll
    for (int m = 0; m < 2; ++m) {
#pragma unroll
        for (int n = 0; n < 2; ++n) {
            int col  = bcol + wc + n * 16 + l15;
            int row0 = brow + wr + m * 16 + kg * 4;
            if (z == 0) {
                float bv = bq[col];
#pragma unroll
                for (int j = 0; j < 4; ++j)
                    FQ[(size_t)(row0 + j) * DIM + col] = acc[m][n][j] + bv;
            } else if (z == 1) {
#pragma unroll
                for (int j = 0; j < 4; ++j)
                    FKb[(size_t)(row0 + j) * DIM + col] = (u16)f2bf(acc[m][n][j]);
            } else if (z == 2) {
#pragma unroll
                for (int j = 0; j < 4; ++j)
                    FVb[(size_t)(row0 + j) * DIM + col] = (u16)f2bf(acc[m][n][j]);
            } else if (z == 4) {
                float bv = be[col];
#pragma unroll
                for (int j = 0; j < 4; ++j)
                    Z0[(size_t)(row0 + j) * DIM + col] = acc[m][n][j] + bv;
            } else {
                if (row0 + 3 < DIM) {
                    ull pk =
                          (ull)f2bf(acc[m][n][0])
                        | ((ull)f2bf(acc[m][n][1]) << 16)
                        | ((ull)f2bf(acc[m][n][2]) << 32)
                        | ((ull)f2bf(acc[m][n][3]) << 48);
                    *(ull*)&WeffT[(size_t)col * DIM + row0] = pk;
                } else {
#pragma unroll
                    for (int j = 0; j < 4; ++j) {
                        int row = row0 + j;
                        if (row < DIM)       WeffT[(size_t)col * DIM + row] = (u16)f2bf(acc[m][n][j]);
                        else if (row == DIM) c_e[col] = acc[m][n][j];
                    }
                }
            }
        }
    }
}

// ---------------------------------------------------------------------------
// Final GEMM: Z1 = Ob @ WeffT + c_e  (fp32 out, single pass)
// ---------------------------------------------------------------------------
__global__ __launch_bounds__(256) void gemm_z1_k(
    const u16* __restrict__ Ob, const u16* __restrict__ WeffT,
    const float* __restrict__ c_e, float* __restrict__ Z1)
{
    __shared__ short As[64][72];
    __shared__ short Bs[64][72];

    int tid  = threadIdx.x;
    int wave = tid >> 6, lane = tid & 63;
    int wr = (wave >> 1) * 32, wc = (wave & 1) * 32;
    int l15 = lane & 15, kg = lane >> 4;
    int brow = blockIdx.y * 64, bcol = blockIdx.x * 64;

    f32x4 acc[2][2] = {};

    int srow = tid >> 3;
    int scol = (tid & 7) * 8;

    for (int k0 = 0; k0 < DIM; k0 += 64) {
#pragma unroll
        for (int s = 0; s < 2; ++s) {
            int r = srow + s * 32;
            *(short8*)&As[r][scol] = *(const short8*)&Ob[(size_t)(brow + r) * DIM + k0 + scol];
            *(short8*)&Bs[r][scol] = *(const short8*)&WeffT[(size_t)(bcol + r) * DIM + k0 + scol];
        }
        __syncthreads();
#pragma unroll
        for (int kk = 0; kk < 2; ++kk) {
            short8 a0 = *(const short8*)&As[wr + l15][kk * 32 + kg * 8];
            short8 a1 = *(const short8*)&As[wr + 16 + l15][kk * 32 + kg * 8];
            short8 b0 = *(const short8*)&Bs[wc + l15][kk * 32 + kg * 8];
            short8 b1 = *(const short8*)&Bs[wc + 16 + l15][kk * 32 + kg * 8];
            acc[0][0] = __builtin_amdgcn_mfma_f32_16x16x32_bf16(a0, b0, acc[0][0], 0, 0, 0);
            acc[0][1] = __builtin_amdgcn_mfma_f32_16x16x32_bf16(a0, b1, acc[0][1], 0, 0, 0);
            acc[1][0] = __builtin_amdgcn_mfma_f32_16x16x32_bf16(a1, b0, acc[1][0], 0, 0, 0);
            acc[1][1] = __builtin_amdgcn_mfma_f32_16x16x32_bf16(a1, b1, acc[1][1], 0, 0, 0);
        }
        __syncthreads();
    }

#pragma unroll
    for (int m = 0; m < 2; ++m) {
#pragma unroll
        for (int n = 0; n < 2; ++n) {
            int col = bcol + wc + n * 16 + l15;
            float bv = c_e[col];
#pragma unroll
            for (int j = 0; j < 4; ++j) {
                int row = brow + wr + m * 16 + kg * 4 + j;
                Z1[(size_t)row * DIM + col] = acc[m][n][j] + bv;
            }
        }
    }
}

// ---------------------------------------------------------------------------
// Fused neighbor attention, shuffle-free score phase. 512 threads/block.
// ---------------------------------------------------------------------------
__global__ __launch_bounds__(512) void attn_k(
    const float* __restrict__ FQ, const u16* __restrict__ FKb, const u16* __restrict__ FVb,
    const int* __restrict__ idxb, const float* __restrict__ distb,
    const float* __restrict__ bk, const float* __restrict__ bv,
    u16* __restrict__ O)
{
    int bn = blockIdx.x;
    int b  = bn >> 9;
    int tid = threadIdx.x;
    int wv = tid >> 6, lane = tid & 63;

    __shared__ float qlds[NH][104];
    __shared__ int   s_idx[KNN];
    __shared__ float s_dist[KNN];
    __shared__ float s_sc[NH][68];
    __shared__ float s_att[NH][68];
    __shared__ float s_qh[NH][2];
    __shared__ float s_sd[NH];

    if (tid < KNN) {
        s_idx[tid]  = idxb[(size_t)bn * KNN + tid];
        s_dist[tid] = distb[(size_t)bn * KNN + tid];
    }
    const float* qrow = FQ + (size_t)bn * DIM;
    {
        int d = tid;
        if (d < DIM) qlds[d / HDIM][d % HDIM] = qrow[d];
        int d2 = tid + 512;
        if (d2 < DIM) qlds[d2 / HDIM][d2 % HDIM] = qrow[d2];
    }
    __syncthreads();

    {
        int h = wv;
        const u16* wdk = FKb + (size_t)MROWS * DIM + h * HDIM;
        const u16* ckr = FKb + (size_t)(MROWS + 1) * DIM + h * HDIM;
        const float* bkh = bk + h * HDIM;
        float q = qlds[h][lane];
        float pw = q * bf2f(wdk[lane]);
        float pc = q * (bf2f(ckr[lane]) + bkh[lane]);
        if (lane < HDIM - 64) {
            float q2 = qlds[h][lane + 64];
            pw = fmaf(q2, bf2f(wdk[lane + 64]), pw);
            pc = fmaf(q2, bf2f(ckr[lane + 64]) + bkh[lane + 64], pc);
        }
#pragma unroll
        for (int off = 32; off; off >>= 1) {
            pw += __shfl_xor(pw, off);
            pc += __shfl_xor(pc, off);
        }
        if (lane == 0) { s_qh[h][0] = pw; s_qh[h][1] = pc; }
    }

    {
        int j = tid >> 3, h = tid & 7;
        const u16* kr = FKb + (size_t)(b * NPTS + s_idx[j]) * DIM + h * HDIM;
        const uint4* kr4 = (const uint4*)kr;
        float a0 = 0.f, a1 = 0.f, a2 = 0.f, a3 = 0.f;
#pragma unroll
        for (int i = 0; i < 12; ++i) {
            uint4 kv = kr4[i];
            float4 qa = *(const float4*)&qlds[h][i * 8];
            float4 qb = *(const float4*)&qlds[h][i * 8 + 4];
            a0 = fmaf(qa.x, __uint_as_float(kv.x << 16), a0);
            a1 = fmaf(qa.y, __uint_as_float(kv.x & 0xffff0000u), a1);
            a2 = fmaf(qa.z, __uint_as_float(kv.y << 16), a2);
            a3 = fmaf(qa.w, __uint_as_float(kv.y & 0xffff0000u), a3);
            a0 = fmaf(qb.x, __uint_as_float(kv.z << 16), a0);
            a1 = fmaf(qb.y, __uint_as_float(kv.z & 0xffff0000u), a1);
            a2 = fmaf(qb.z, __uint_as_float(kv.w << 16), a2);
            a3 = fmaf(qb.w, __uint_as_float(kv.w & 0xffff0000u), a3);
        }
        s_sc[h][j] = (a0 + a1) + (a2 + a3);
    }
    __syncthreads();

    {
        int h = wv, j = lane;
        const float invs = 0.10206207261596575f;
        float qwdk = s_qh[h][0], qck = s_qh[h][1];
        float dj = s_dist[j];
        float sc = (s_sc[h][j] + dj * qwdk + qck) * invs;
        float mx = sc;
#pragma unroll
        for (int off = 32; off; off >>= 1) mx = fmaxf(mx, __shfl_xor(mx, off));
        float ev = __expf(sc - mx);
        float sum = ev;
#pragma unroll
        for (int off = 32; off; off >>= 1) sum += __shfl_xor(sum, off);
        float att = ev / sum;
        s_att[h][j] = att;
        float sd = att * dj;
#pragma unroll
        for (int off = 32; off; off >>= 1) sd += __shfl_xor(sd, off);
        if (lane == 0) s_sd[h] = sd;
    }
    __syncthreads();

    if (tid < 384) {
        int d0 = tid * 2;
        int h  = d0 / HDIM;
        const float* attp = s_att[h];
        const size_t basev = (size_t)(b * NPTS) * DIM + d0;
        float o0 = 0.f, o1 = 0.f;
#pragma unroll 4
        for (int j = 0; j < KNN; ++j) {
            unsigned pv = *(const unsigned*)&FVb[basev + (size_t)s_idx[j] * DIM];
            float a = attp[j];
            o0 = fmaf(a, __uint_as_float(pv << 16), o0);
            o1 = fmaf(a, __uint_as_float(pv & 0xffff0000u), o1);
        }
        const u16* wdv = FVb + (size_t)MROWS * DIM;
        const u16* cvr = FVb + (size_t)(MROWS + 1) * DIM;
        float sdh = s_sd[h];
        o0 += sdh * bf2f(wdv[d0])     + (bf2f(cvr[d0])     + bv[d0]);
        o1 += sdh * bf2f(wdv[d0 + 1]) + (bf2f(cvr[d0 + 1]) + bv[d0 + 1]);
        unsigned po = f2bf(o0) | (f2bf(o1) << 16);
        *(unsigned*)&O[(size_t)bn * DIM + d0] = po;
    }
}

// ---------------------------------------------------------------------------
// LayerNorm + SiLU; x = Z0 + Z1. 192 threads, float4/thread.
// ---------------------------------------------------------------------------
__global__ __launch_bounds__(192) void ln_silu_k(
    const float* __restrict__ Z0, const float* __restrict__ Z1,
    const float* __restrict__ g, const float* __restrict__ bta,
    float* __restrict__ out)
{
    int bn = blockIdx.x, tid = threadIdx.x;
    size_t ro = (size_t)bn * DIM;
    int e0 = tid * 4;
    float4 x = *(const float4*)&Z0[ro + e0];
    {
        float4 p = *(const float4*)&Z1[ro + e0];
        x.x += p.x; x.y += p.y; x.z += p.z; x.w += p.w;
    }
    float s  = (x.x + x.y) + (x.z + x.w);
    float ss = (x.x * x.x + x.y * x.y) + (x.z * x.z + x.w * x.w);
    __shared__ float red[3][2];
#pragma unroll
    for (int off = 32; off; off >>= 1) {
        s  += __shfl_xor(s, off);
        ss += __shfl_xor(ss, off);
    }
    int w = tid >> 6;
    if ((tid & 63) == 0) { red[w][0] = s; red[w][1] = ss; }
    __syncthreads();
    s  = red[0][0] + red[1][0] + red[2][0];
    ss = red[0][1] + red[1][1] + red[2][1];
    float mean = s * (1.0f / DIM);
    float var  = ss * (1.0f / DIM) - mean * mean;
    float rstd = rsqrtf(var + 1e-5f);
    float4 gv = *(const float4*)&g[e0];
    float4 bv = *(const float4*)&bta[e0];
    float4 y;
    y.x = (x.x - mean) * rstd * gv.x + bv.x;
    y.y = (x.y - mean) * rstd * gv.y + bv.y;
    y.z = (x.z - mean) * rstd * gv.z + bv.z;
    y.w = (x.w - mean) * rstd * gv.w + bv.w;
    float4 o;
    o.x = y.x / (1.0f + __expf(-y.x));
    o.y = y.y / (1.0f + __expf(-y.y));
    o.z = y.z / (1.0f + __expf(-y.z));
    o.w = y.w / (1.0f + __expf(-y.w));
    *(float4*)&out[ro + e0] = o;
}

// ---------------------------------------------------------------------------
extern "C" void kernel_launch(void* const* d_in, const int* in_sizes, int n_in,
                              void* d_out, int out_size, void* d_ws, size_t ws_size,
                              hipStream_t stream)
{
    const float* features = (const float*)d_in[0];
    const float* pts      = (const float*)d_in[1];
    const float* Wd       = (const float*)d_in[2];
    const float* bd       = (const float*)d_in[3];
    const float* Wq       = (const float*)d_in[4];
    const float* bq       = (const float*)d_in[5];
    const float* Wk       = (const float*)d_in[6];
    const float* bk       = (const float*)d_in[7];
    const float* Wv       = (const float*)d_in[8];
    const float* bv       = (const float*)d_in[9];
    const float* Wo       = (const float*)d_in[10];
    const float* bo       = (const float*)d_in[11];
    const float* We       = (const float*)d_in[12];
    const float* be       = (const float*)d_in[13];
    const float* g_ln     = (const float*)d_in[14];
    const float* b_ln     = (const float*)d_in[15];

    const size_t MAT  = (size_t)MROWS * DIM;   // 786432
    const size_t MATP = (size_t)MPAD  * DIM;   // 835584

    float* ws = (float*)d_ws;
    float* FQ    = ws;                       // [1088][768] f32
    u16*   FKb   = (u16*)(ws + MATP);        // [1088][768] bf16 (rows 1024/1025 = wdk/ck)
    u16*   FVb   = FKb + MATP;               // [1088][768] bf16
    u16*   Fb    = FVb + MATP;               // [1088][768] bf16 (features + Wd/bd rows)
    u16*   Ob    = Fb + MATP;                // [1024][768] bf16 (attention output)
    u16*   Wob   = Ob + MAT;                 // [832][768] bf16 ([Wo; bo; 0])
    u16*   W3    = Wob + (size_t)WOROWS * DIM;  // 5 x [768][768] bf16 transposed
    u16*   WeffT = W3 + 5 * WSQ;             // [768][768] bf16 (Wo@WeBot)^T
    float* c_e   = (float*)(WeffT + WSQ);    // [768] f32 (bo@WeBot)
    int*   idxb  = (int*)(c_e + DIM);
    float* distb = (float*)(idxb + (size_t)MROWS * KNN);
    float* Z0    = distb + (size_t)MROWS * KNN;   // [1024][768] f32
    float* Z1    = Z0 + MAT;                      // [1024][768] f32

    // 1) pure-convert prep
    mega_prep_k<<<2160, 256, 0, stream>>>(features, Wd, bd, Wq, Wk, Wv, Wo, bo, We,
                                          Fb, Wob, W3);
    // 2) topk standalone (LDS bitonic)
    topk_k<<<MROWS, 256, 0, stream>>>(pts, idxb, distb);
    // 3) QKV + Weff + Z0 GEMMs standalone
    gemm5_k<<<1008, 256, 0, stream>>>(
        Fb, Wob, W3, bq, be, FQ, FKb, FVb, WeffT, c_e, Z0);
    // 4) fused neighbor attention
    attn_k<<<MROWS, 512, 0, stream>>>(FQ, FKb, FVb, idxb, distb, bk, bv, Ob);
    // 5) Z1 = Ob @ WeffT + c_e
    gemm_z1_k<<<dim3(12, 16), 256, 0, stream>>>(Ob, WeffT, c_e, Z1);
    // 6) LayerNorm(Z0 + Z1) + SiLU
    ln_silu_k<<<MROWS, 192, 0, stream>>>(Z0, Z1, g_ln, b_ln, (float*)d_out);
}

// Round 14
// 71.281 us; speedup vs baseline: 1.2863x; 1.2863x over previous
//
#include <hip/hip_runtime.h>
#include <math.h>

#define NPTS 512
#define DIM  768
#define KNN  64
#define NH   8
#define HDIM 96
#define MROWS 1024   // B*NP
#define MPAD  1088   // MROWS + 2 (Wd,bd rows) padded to 64
#define WOROWS 832   // 768 Wo rows + 1 bo row, padded to 64
#define WSQ   ((size_t)DIM * DIM)

typedef unsigned short u16;
typedef unsigned long long ull;
typedef __attribute__((ext_vector_type(8))) short short8;
typedef __attribute__((ext_vector_type(4))) float f32x4;

__device__ __forceinline__ unsigned f2bf(float f) {
    unsigned u = __float_as_uint(f);
    return (u + 0x7fffu + ((u >> 16) & 1u)) >> 16;   // round-to-nearest-even
}
__device__ __forceinline__ float bf2f(u16 v) {
    return __uint_as_float(((unsigned)v) << 16);
}
__device__ __forceinline__ ull shfl_xor_u64(ull x, int j) {
    unsigned lo = (unsigned)x, hi = (unsigned)(x >> 32);
    lo = __shfl_xor(lo, j); hi = __shfl_xor(hi, j);
    return ((ull)hi << 32) | lo;
}
// merge two ascending sorted-64 lists (this lane's a, partner list b), keep the
// smallest 64 (Batcher bitonic-merge first half); optionally re-sort ascending.
__device__ __forceinline__ ull merge_discard(ull a, ull b, int lane, bool clean) {
    ull rev = shfl_xor_u64(b, 63);            // reverse b across lanes
    ull m = a < rev ? a : rev;                // bitonic seq of the 64 smallest
    if (clean) {
#pragma unroll
        for (int j = 32; j > 0; j >>= 1) {    // bitonic cleanup -> ascending
            ull p = shfl_xor_u64(m, j);
            bool keep_lo = ((lane & j) == 0);
            bool alt = m < p;
            ull lo = alt ? m : p, hi = alt ? p : m;
            m = keep_lo ? lo : hi;
        }
    }
    return m;
}

// ---------------------------------------------------------------------------
// Prep kernel (pure converts): one launch.
//  [0,768)     : features fp32 -> bf16 (Fb rows 0..1023)
//  [768,816)   : Fb rows 1024(Wd) 1025(bd) 1026..1087(zero)
//  [816,1440)  : Wob = bf16([Wo; bo; 0...])  (832x768)
//  [1440,2160) : 5 transposes fp32[k][n] -> bf16 [n][k]: Wq,Wk,Wv,WeTop,WeBot
// ---------------------------------------------------------------------------
__global__ __launch_bounds__(256) void mega_prep_k(
    const float* __restrict__ features,
    const float* __restrict__ Wd, const float* __restrict__ bd,
    const float* __restrict__ Wq, const float* __restrict__ Wk, const float* __restrict__ Wv,
    const float* __restrict__ Wo, const float* __restrict__ bo, const float* __restrict__ We,
    u16* __restrict__ Fb, u16* __restrict__ Wob, u16* __restrict__ W3)
{
    __shared__ float T[64][65];
    int bid = blockIdx.x, tid = threadIdx.x;

    if (bid < 768) {                       // ---- convF
        int i = (bid * 256 + tid) * 4;
        float4 v = *(const float4*)&features[i];
        uint2 o;
        o.x = f2bf(v.x) | (f2bf(v.y) << 16);
        o.y = f2bf(v.z) | (f2bf(v.w) << 16);
        *(uint2*)&Fb[i] = o;
        return;
    }
    if (bid < 816) {                       // ---- extra A rows
        int flat = (bid - 768) * 1024 + tid * 4;   // 64x768 region
        int r = flat / DIM, c = flat - r * DIM;
        uint2 o; o.x = 0u; o.y = 0u;
        if (r == 0) {
            float4 v = *(const float4*)&Wd[c];
            o.x = f2bf(v.x) | (f2bf(v.y) << 16);
            o.y = f2bf(v.z) | (f2bf(v.w) << 16);
        } else if (r == 1) {
            float4 v = *(const float4*)&bd[c];
            o.x = f2bf(v.x) | (f2bf(v.y) << 16);
            o.y = f2bf(v.z) | (f2bf(v.w) << 16);
        }
        *(uint2*)&Fb[(size_t)(MROWS + r) * DIM + c] = o;
        return;
    }
    if (bid < 1440) {                      // ---- Wob = [Wo; bo; zeros]
        int flat = (bid - 816) * 1024 + tid * 4;   // 832x768 region
        int r = flat / DIM, c = flat - r * DIM;
        uint2 o; o.x = 0u; o.y = 0u;
        if (r < DIM) {
            float4 v = *(const float4*)&Wo[(size_t)r * DIM + c];
            o.x = f2bf(v.x) | (f2bf(v.y) << 16);
            o.y = f2bf(v.z) | (f2bf(v.w) << 16);
        } else if (r == DIM) {
            float4 v = *(const float4*)&bo[c];
            o.x = f2bf(v.x) | (f2bf(v.y) << 16);
            o.y = f2bf(v.z) | (f2bf(v.w) << 16);
        }
        *(uint2*)&Wob[(size_t)r * DIM + c] = o;
        return;
    }
    // ---- convT: 5 matrices x 144 (12x12) tile-blocks
    {
        int t = bid - 1440;
        int m = t / 144, r2 = t % 144;
        int by = r2 / 12, bx = r2 % 12;
        const float* S = (m == 0) ? Wq : (m == 1) ? Wk : (m == 2) ? Wv
                       : (m == 3) ? We : (We + WSQ);
        u16* D = W3 + (size_t)m * WSQ;
        int r0 = by * 64, c0 = bx * 64;
#pragma unroll
        for (int i = 0; i < 16; ++i) {
            int lin = tid + i * 256;
            int r = lin >> 6, c = lin & 63;
            T[r][c] = S[(size_t)(r0 + r) * DIM + c0 + c];
        }
        __syncthreads();
#pragma unroll
        for (int i = 0; i < 16; ++i) {
            int lin = tid + i * 256;
            int c = lin >> 6, r = lin & 63;
            D[(size_t)(c0 + c) * DIM + r0 + r] = (u16)f2bf(T[r][c]);
        }
    }
}

// ---------------------------------------------------------------------------
// Combined topk + QKV/Weff/Z0 GEMM launch.
//  bid < 256   : topk — one wave per point, in-register PARTIAL sort:
//                sort 8 lists of 64 (21 stages), then 3 merge-discard rounds
//                (Batcher first-half property). Zero barriers after P stage.
//                Output set unordered — softmax is permutation-invariant.
//  [256,1072)  : GEMM z = (bid-256)/204 (z0:FQ z1:FKb z2:FVb z3:WeffT+c_e)
//  [1072,1264) : GEMM z4: Z0 = Fb @ WeTopT + be
// ---------------------------------------------------------------------------
union alignas(16) GTSm {
    struct { short As[64][72]; short Bs[64][72]; } g;   // 18432 B
    float P[NPTS * 3];                                  // 6144 B
};

__global__ __launch_bounds__(256) void qkvw_topk_k(
    const u16* __restrict__ Fb, const u16* __restrict__ Wob, const u16* __restrict__ W3,
    const float* __restrict__ bq, const float* __restrict__ be,
    const float* __restrict__ pts,
    float* __restrict__ FQ, u16* __restrict__ FKb, u16* __restrict__ FVb,
    u16* __restrict__ WeffT, float* __restrict__ c_e, float* __restrict__ Z0,
    int* __restrict__ idxb, float* __restrict__ distb)
{
    __shared__ GTSm sm;
    int bid = blockIdx.x, tid = threadIdx.x;

    if (bid < 256) {                       // ================= topk =================
        int w = tid >> 6, lane = tid & 63;
        int bn = bid * 4 + w;              // one wave per point
        int b  = bn >> 9;
        int n  = bn & (NPTS - 1);
        const float* pb = pts + (size_t)b * NPTS * 3;
        for (int i = tid; i < NPTS * 3; i += 256) sm.P[i] = pb[i];
        __syncthreads();

        float xn = sm.P[n * 3], yn = sm.P[n * 3 + 1], zn = sm.P[n * 3 + 2];
        float sqn = xn * xn + yn * yn + zn * zn;
        ull key[8];
#pragma unroll
        for (int r = 0; r < 8; ++r) {
            int m = r * 64 + lane;
            float xm = sm.P[m * 3], ym = sm.P[m * 3 + 1], zm = sm.P[m * 3 + 2];
            float d2 = sqn + (xm * xm + ym * ym + zm * zm)
                     - 2.0f * (xn * xm + yn * ym + zn * zm);
            unsigned db = __float_as_uint(fmaxf(d2, 0.0f));
            key[r] = ((ull)db << 32) | (unsigned)m;
        }

        // phase 1: sort each register's 64-element list ascending (21 stages)
#pragma unroll
        for (int k = 2; k <= 64; k <<= 1) {
#pragma unroll
            for (int j = k >> 1; j > 0; j >>= 1) {
#pragma unroll
                for (int r = 0; r < 8; ++r) {
                    ull p = shfl_xor_u64(key[r], j);
                    bool up = ((lane & k) == 0);          // k==64: always true
                    bool keep_lo = up == ((lane & j) == 0);
                    bool alt = key[r] < p;
                    ull lo = alt ? key[r] : p, hi = alt ? p : key[r];
                    key[r] = keep_lo ? lo : hi;
                }
            }
        }

        // phase 2-4: merge-discard tree 8 -> 4 -> 2 -> 1 lists of 64
        key[0] = merge_discard(key[0], key[4], lane, true);
        key[1] = merge_discard(key[1], key[5], lane, true);
        key[2] = merge_discard(key[2], key[6], lane, true);
        key[3] = merge_discard(key[3], key[7], lane, true);
        key[0] = merge_discard(key[0], key[2], lane, true);
        key[1] = merge_discard(key[1], key[3], lane, true);
        key[0] = merge_discard(key[0], key[1], lane, false);  // set only

        ull k0 = key[0];
        idxb[(size_t)bn * KNN + lane]  = (int)(k0 & 0xffffffffu);
        distb[(size_t)bn * KNN + lane] = sqrtf(__uint_as_float((unsigned)(k0 >> 32)));
        return;
    }

    // ================= GEMM =================
    int bid2 = bid - 256;
    int z, by, bx;
    if (bid2 < 816) {
        z = bid2 / 204;
        int rem = bid2 - z * 204;
        by = rem / 12; bx = rem - by * 12;
        if (z == 0 && by >= 16) return;
        if (z == 3 && by >= 13) return;
    } else {
        z = 4;
        int rem = bid2 - 816;
        by = rem / 12; bx = rem - by * 12;
    }
    const u16* A  = (z == 3) ? Wob : Fb;
    const u16* BT = W3 + (size_t)((z == 3) ? 4 : (z == 4) ? 3 : z) * WSQ;

    int wave = tid >> 6, lane = tid & 63;
    int wr = (wave >> 1) * 32, wc = (wave & 1) * 32;
    int l15 = lane & 15, kg = lane >> 4;
    int brow = by * 64, bcol = bx * 64;

    f32x4 acc[2][2] = {};

    int srow = tid >> 3;            // 0..31
    int scol = (tid & 7) * 8;       // 0,8,..,56

    for (int k0 = 0; k0 < DIM; k0 += 64) {
#pragma unroll
        for (int s = 0; s < 2; ++s) {
            int r = srow + s * 32;
            *(short8*)&sm.g.As[r][scol] = *(const short8*)&A[(size_t)(brow + r) * DIM + k0 + scol];
            *(short8*)&sm.g.Bs[r][scol] = *(const short8*)&BT[(size_t)(bcol + r) * DIM + k0 + scol];
        }
        __syncthreads();
#pragma unroll
        for (int kk = 0; kk < 2; ++kk) {
            short8 a0 = *(const short8*)&sm.g.As[wr + l15][kk * 32 + kg * 8];
            short8 a1 = *(const short8*)&sm.g.As[wr + 16 + l15][kk * 32 + kg * 8];
            short8 b0 = *(const short8*)&sm.g.Bs[wc + l15][kk * 32 + kg * 8];
            short8 b1 = *(const short8*)&sm.g.Bs[wc + 16 + l15][kk * 32 + kg * 8];
            acc[0][0] = __builtin_amdgcn_mfma_f32_16x16x32_bf16(a0, b0, acc[0][0], 0, 0, 0);
            acc[0][1] = __builtin_amdgcn_mfma_f32_16x16x32_bf16(a0, b1, acc[0][1], 0, 0, 0);
            acc[1][0] = __builtin_amdgcn_mfma_f32_16x16x32_bf16(a1, b0, acc[1][0], 0, 0, 0);
            acc[1][1] = __builtin_amdgcn_mfma_f32_16x16x32_bf16(a1, b1, acc[1][1], 0, 0, 0);
        }
        __syncthreads();
    }

    // D layout: col = lane&15, row = (lane>>4)*4 + j
#pragma unroll
    for (int m = 0; m < 2; ++m) {
#pragma unroll
        for (int n = 0; n < 2; ++n) {
            int col  = bcol + wc + n * 16 + l15;
            int row0 = brow + wr + m * 16 + kg * 4;
            if (z == 0) {
                float bv = bq[col];
#pragma unroll
                for (int j = 0; j < 4; ++j)
                    FQ[(size_t)(row0 + j) * DIM + col] = acc[m][n][j] + bv;
            } else if (z == 1) {
#pragma unroll
                for (int j = 0; j < 4; ++j)
                    FKb[(size_t)(row0 + j) * DIM + col] = (u16)f2bf(acc[m][n][j]);
            } else if (z == 2) {
#pragma unroll
                for (int j = 0; j < 4; ++j)
                    FVb[(size_t)(row0 + j) * DIM + col] = (u16)f2bf(acc[m][n][j]);
            } else if (z == 4) {
                float bv = be[col];
#pragma unroll
                for (int j = 0; j < 4; ++j)
                    Z0[(size_t)(row0 + j) * DIM + col] = acc[m][n][j] + bv;
            } else {
                if (row0 + 3 < DIM) {
                    ull pk =
                          (ull)f2bf(acc[m][n][0])
                        | ((ull)f2bf(acc[m][n][1]) << 16)
                        | ((ull)f2bf(acc[m][n][2]) << 32)
                        | ((ull)f2bf(acc[m][n][3]) << 48);
                    *(ull*)&WeffT[(size_t)col * DIM + row0] = pk;
                } else {
#pragma unroll
                    for (int j = 0; j < 4; ++j) {
                        int row = row0 + j;
                        if (row < DIM)       WeffT[(size_t)col * DIM + row] = (u16)f2bf(acc[m][n][j]);
                        else if (row == DIM) c_e[col] = acc[m][n][j];
                    }
                }
            }
        }
    }
}

// ---------------------------------------------------------------------------
// Final GEMM: Z1 = Ob @ WeffT + c_e  (fp32 out, single pass)
// ---------------------------------------------------------------------------
__global__ __launch_bounds__(256) void gemm_z1_k(
    const u16* __restrict__ Ob, const u16* __restrict__ WeffT,
    const float* __restrict__ c_e, float* __restrict__ Z1)
{
    __shared__ short As[64][72];
    __shared__ short Bs[64][72];

    int tid  = threadIdx.x;
    int wave = tid >> 6, lane = tid & 63;
    int wr = (wave >> 1) * 32, wc = (wave & 1) * 32;
    int l15 = lane & 15, kg = lane >> 4;
    int brow = blockIdx.y * 64, bcol = blockIdx.x * 64;

    f32x4 acc[2][2] = {};

    int srow = tid >> 3;
    int scol = (tid & 7) * 8;

    for (int k0 = 0; k0 < DIM; k0 += 64) {
#pragma unroll
        for (int s = 0; s < 2; ++s) {
            int r = srow + s * 32;
            *(short8*)&As[r][scol] = *(const short8*)&Ob[(size_t)(brow + r) * DIM + k0 + scol];
            *(short8*)&Bs[r][scol] = *(const short8*)&WeffT[(size_t)(bcol + r) * DIM + k0 + scol];
        }
        __syncthreads();
#pragma unroll
        for (int kk = 0; kk < 2; ++kk) {
            short8 a0 = *(const short8*)&As[wr + l15][kk * 32 + kg * 8];
            short8 a1 = *(const short8*)&As[wr + 16 + l15][kk * 32 + kg * 8];
            short8 b0 = *(const short8*)&Bs[wc + l15][kk * 32 + kg * 8];
            short8 b1 = *(const short8*)&Bs[wc + 16 + l15][kk * 32 + kg * 8];
            acc[0][0] = __builtin_amdgcn_mfma_f32_16x16x32_bf16(a0, b0, acc[0][0], 0, 0, 0);
            acc[0][1] = __builtin_amdgcn_mfma_f32_16x16x32_bf16(a0, b1, acc[0][1], 0, 0, 0);
            acc[1][0] = __builtin_amdgcn_mfma_f32_16x16x32_bf16(a1, b0, acc[1][0], 0, 0, 0);
            acc[1][1] = __builtin_amdgcn_mfma_f32_16x16x32_bf16(a1, b1, acc[1][1], 0, 0, 0);
        }
        __syncthreads();
    }

#pragma unroll
    for (int m = 0; m < 2; ++m) {
#pragma unroll
        for (int n = 0; n < 2; ++n) {
            int col = bcol + wc + n * 16 + l15;
            float bv = c_e[col];
#pragma unroll
            for (int j = 0; j < 4; ++j) {
                int row = brow + wr + m * 16 + kg * 4 + j;
                Z1[(size_t)row * DIM + col] = acc[m][n][j] + bv;
            }
        }
    }
}

// ---------------------------------------------------------------------------
// Fused neighbor attention, shuffle-free score phase. 512 threads/block.
// ---------------------------------------------------------------------------
__global__ __launch_bounds__(512) void attn_k(
    const float* __restrict__ FQ, const u16* __restrict__ FKb, const u16* __restrict__ FVb,
    const int* __restrict__ idxb, const float* __restrict__ distb,
    const float* __restrict__ bk, const float* __restrict__ bv,
    u16* __restrict__ O)
{
    int bn = blockIdx.x;
    int b  = bn >> 9;
    int tid = threadIdx.x;
    int wv = tid >> 6, lane = tid & 63;

    __shared__ float qlds[NH][104];
    __shared__ int   s_idx[KNN];
    __shared__ float s_dist[KNN];
    __shared__ float s_sc[NH][68];
    __shared__ float s_att[NH][68];
    __shared__ float s_qh[NH][2];
    __shared__ float s_sd[NH];

    if (tid < KNN) {
        s_idx[tid]  = idxb[(size_t)bn * KNN + tid];
        s_dist[tid] = distb[(size_t)bn * KNN + tid];
    }
    const float* qrow = FQ + (size_t)bn * DIM;
    {
        int d = tid;
        if (d < DIM) qlds[d / HDIM][d % HDIM] = qrow[d];
        int d2 = tid + 512;
        if (d2 < DIM) qlds[d2 / HDIM][d2 % HDIM] = qrow[d2];
    }
    __syncthreads();

    {
        int h = wv;
        const u16* wdk = FKb + (size_t)MROWS * DIM + h * HDIM;
        const u16* ckr = FKb + (size_t)(MROWS + 1) * DIM + h * HDIM;
        const float* bkh = bk + h * HDIM;
        float q = qlds[h][lane];
        float pw = q * bf2f(wdk[lane]);
        float pc = q * (bf2f(ckr[lane]) + bkh[lane]);
        if (lane < HDIM - 64) {
            float q2 = qlds[h][lane + 64];
            pw = fmaf(q2, bf2f(wdk[lane + 64]), pw);
            pc = fmaf(q2, bf2f(ckr[lane + 64]) + bkh[lane + 64], pc);
        }
#pragma unroll
        for (int off = 32; off; off >>= 1) {
            pw += __shfl_xor(pw, off);
            pc += __shfl_xor(pc, off);
        }
        if (lane == 0) { s_qh[h][0] = pw; s_qh[h][1] = pc; }
    }

    {
        int j = tid >> 3, h = tid & 7;
        const u16* kr = FKb + (size_t)(b * NPTS + s_idx[j]) * DIM + h * HDIM;
        const uint4* kr4 = (const uint4*)kr;
        float a0 = 0.f, a1 = 0.f, a2 = 0.f, a3 = 0.f;
#pragma unroll
        for (int i = 0; i < 12; ++i) {
            uint4 kv = kr4[i];
            float4 qa = *(const float4*)&qlds[h][i * 8];
            float4 qb = *(const float4*)&qlds[h][i * 8 + 4];
            a0 = fmaf(qa.x, __uint_as_float(kv.x << 16), a0);
            a1 = fmaf(qa.y, __uint_as_float(kv.x & 0xffff0000u), a1);
            a2 = fmaf(qa.z, __uint_as_float(kv.y << 16), a2);
            a3 = fmaf(qa.w, __uint_as_float(kv.y & 0xffff0000u), a3);
            a0 = fmaf(qb.x, __uint_as_float(kv.z << 16), a0);
            a1 = fmaf(qb.y, __uint_as_float(kv.z & 0xffff0000u), a1);
            a2 = fmaf(qb.z, __uint_as_float(kv.w << 16), a2);
            a3 = fmaf(qb.w, __uint_as_float(kv.w & 0xffff0000u), a3);
        }
        s_sc[h][j] = (a0 + a1) + (a2 + a3);
    }
    __syncthreads();

    {
        int h = wv, j = lane;
        const float invs = 0.10206207261596575f;
        float qwdk = s_qh[h][0], qck = s_qh[h][1];
        float dj = s_dist[j];
        float sc = (s_sc[h][j] + dj * qwdk + qck) * invs;
        float mx = sc;
#pragma unroll
        for (int off = 32; off; off >>= 1) mx = fmaxf(mx, __shfl_xor(mx, off));
        float ev = __expf(sc - mx);
        float sum = ev;
#pragma unroll
        for (int off = 32; off; off >>= 1) sum += __shfl_xor(sum, off);
        float att = ev / sum;
        s_att[h][j] = att;
        float sd = att * dj;
#pragma unroll
        for (int off = 32; off; off >>= 1) sd += __shfl_xor(sd, off);
        if (lane == 0) s_sd[h] = sd;
    }
    __syncthreads();

    if (tid < 384) {
        int d0 = tid * 2;
        int h  = d0 / HDIM;
        const float* attp = s_att[h];
        const size_t basev = (size_t)(b * NPTS) * DIM + d0;
        float o0 = 0.f, o1 = 0.f;
#pragma unroll 4
        for (int j = 0; j < KNN; ++j) {
            unsigned pv = *(const unsigned*)&FVb[basev + (size_t)s_idx[j] * DIM];
            float a = attp[j];
            o0 = fmaf(a, __uint_as_float(pv << 16), o0);
            o1 = fmaf(a, __uint_as_float(pv & 0xffff0000u), o1);
        }
        const u16* wdv = FVb + (size_t)MROWS * DIM;
        const u16* cvr = FVb + (size_t)(MROWS + 1) * DIM;
        float sdh = s_sd[h];
        o0 += sdh * bf2f(wdv[d0])     + (bf2f(cvr[d0])     + bv[d0]);
        o1 += sdh * bf2f(wdv[d0 + 1]) + (bf2f(cvr[d0 + 1]) + bv[d0 + 1]);
        unsigned po = f2bf(o0) | (f2bf(o1) << 16);
        *(unsigned*)&O[(size_t)bn * DIM + d0] = po;
    }
}

// ---------------------------------------------------------------------------
// LayerNorm + SiLU; x = Z0 + Z1. 192 threads, float4/thread.
// ---------------------------------------------------------------------------
__global__ __launch_bounds__(192) void ln_silu_k(
    const float* __restrict__ Z0, const float* __restrict__ Z1,
    const float* __restrict__ g, const float* __restrict__ bta,
    float* __restrict__ out)
{
    int bn = blockIdx.x, tid = threadIdx.x;
    size_t ro = (size_t)bn * DIM;
    int e0 = tid * 4;
    float4 x = *(const float4*)&Z0[ro + e0];
    {
        float4 p = *(const float4*)&Z1[ro + e0];
        x.x += p.x; x.y += p.y; x.z += p.z; x.w += p.w;
    }
    float s  = (x.x + x.y) + (x.z + x.w);
    float ss = (x.x * x.x + x.y * x.y) + (x.z * x.z + x.w * x.w);
    __shared__ float red[3][2];
#pragma unroll
    for (int off = 32; off; off >>= 1) {
        s  += __shfl_xor(s, off);
        ss += __shfl_xor(ss, off);
    }
    int w = tid >> 6;
    if ((tid & 63) == 0) { red[w][0] = s; red[w][1] = ss; }
    __syncthreads();
    s  = red[0][0] + red[1][0] + red[2][0];
    ss = red[0][1] + red[1][1] + red[2][1];
    float mean = s * (1.0f / DIM);
    float var  = ss * (1.0f / DIM) - mean * mean;
    float rstd = rsqrtf(var + 1e-5f);
    float4 gv = *(const float4*)&g[e0];
    float4 bv = *(const float4*)&bta[e0];
    float4 y;
    y.x = (x.x - mean) * rstd * gv.x + bv.x;
    y.y = (x.y - mean) * rstd * gv.y + bv.y;
    y.z = (x.z - mean) * rstd * gv.z + bv.z;
    y.w = (x.w - mean) * rstd * gv.w + bv.w;
    float4 o;
    o.x = y.x / (1.0f + __expf(-y.x));
    o.y = y.y / (1.0f + __expf(-y.y));
    o.z = y.z / (1.0f + __expf(-y.z));
    o.w = y.w / (1.0f + __expf(-y.w));
    *(float4*)&out[ro + e0] = o;
}

// ---------------------------------------------------------------------------
extern "C" void kernel_launch(void* const* d_in, const int* in_sizes, int n_in,
                              void* d_out, int out_size, void* d_ws, size_t ws_size,
                              hipStream_t stream)
{
    const float* features = (const float*)d_in[0];
    const float* pts      = (const float*)d_in[1];
    const float* Wd       = (const float*)d_in[2];
    const float* bd       = (const float*)d_in[3];
    const float* Wq       = (const float*)d_in[4];
    const float* bq       = (const float*)d_in[5];
    const float* Wk       = (const float*)d_in[6];
    const float* bk       = (const float*)d_in[7];
    const float* Wv       = (const float*)d_in[8];
    const float* bv       = (const float*)d_in[9];
    const float* Wo       = (const float*)d_in[10];
    const float* bo       = (const float*)d_in[11];
    const float* We       = (const float*)d_in[12];
    const float* be       = (const float*)d_in[13];
    const float* g_ln     = (const float*)d_in[14];
    const float* b_ln     = (const float*)d_in[15];

    const size_t MAT  = (size_t)MROWS * DIM;   // 786432
    const size_t MATP = (size_t)MPAD  * DIM;   // 835584

    float* ws = (float*)d_ws;
    float* FQ    = ws;                       // [1088][768] f32
    u16*   FKb   = (u16*)(ws + MATP);        // [1088][768] bf16 (rows 1024/1025 = wdk/ck)
    u16*   FVb   = FKb + MATP;               // [1088][768] bf16
    u16*   Fb    = FVb + MATP;               // [1088][768] bf16 (features + Wd/bd rows)
    u16*   Ob    = Fb + MATP;                // [1024][768] bf16 (attention output)
    u16*   Wob   = Ob + MAT;                 // [832][768] bf16 ([Wo; bo; 0])
    u16*   W3    = Wob + (size_t)WOROWS * DIM;  // 5 x [768][768] bf16 transposed
    u16*   WeffT = W3 + 5 * WSQ;             // [768][768] bf16 (Wo@WeBot)^T
    float* c_e   = (float*)(WeffT + WSQ);    // [768] f32 (bo@WeBot)
    int*   idxb  = (int*)(c_e + DIM);
    float* distb = (float*)(idxb + (size_t)MROWS * KNN);
    float* Z0    = distb + (size_t)MROWS * KNN;   // [1024][768] f32
    float* Z1    = Z0 + MAT;                      // [1024][768] f32

    // 1) pure-convert prep
    mega_prep_k<<<2160, 256, 0, stream>>>(features, Wd, bd, Wq, Wk, Wv, Wo, bo, We,
                                          Fb, Wob, W3);
    // 2) topk (wave partial-select, first) + QKV + Weff + Z0 GEMMs, one launch
    qkvw_topk_k<<<1264, 256, 0, stream>>>(
        Fb, Wob, W3, bq, be, pts, FQ, FKb, FVb, WeffT, c_e, Z0, idxb, distb);
    // 3) fused neighbor attention
    attn_k<<<MROWS, 512, 0, stream>>>(FQ, FKb, FVb, idxb, distb, bk, bv, Ob);
    // 4) Z1 = Ob @ WeffT + c_e
    gemm_z1_k<<<dim3(12, 16), 256, 0, stream>>>(Ob, WeffT, c_e, Z1);
    // 5) LayerNorm(Z0 + Z1) + SiLU
    ln_silu_k<<<MROWS, 192, 0, stream>>>(Z0, Z1, g_ln, b_ln, (float*)d_out);
}

// Round 15
// 67.767 us; speedup vs baseline: 1.3530x; 1.0519x over previous
//
#include <hip/hip_runtime.h>
#include <math.h>

#define NPTS 512
#define DIM  768
#define KNN  64
#define NH   8
#define HDIM 96
#define MROWS 1024   // B*NP
#define MPAD  1088   // MROWS + 2 (Wd,bd rows) padded to 64
#define WOROWS 832   // 768 Wo rows + 1 bo row, padded to 64
#define WSQ   ((size_t)DIM * DIM)

typedef unsigned short u16;
typedef unsigned long long ull;
typedef __attribute__((ext_vector_type(8))) short short8;
typedef __attribute__((ext_vector_type(4))) float f32x4;

__device__ __forceinline__ unsigned f2bf(float f) {
    unsigned u = __float_as_uint(f);
    return (u + 0x7fffu + ((u >> 16) & 1u)) >> 16;   // round-to-nearest-even
}
__device__ __forceinline__ float bf2f(u16 v) {
    return __uint_as_float(((unsigned)v) << 16);
}
__device__ __forceinline__ void gload_lds16(const void* g, void* l) {
    __builtin_amdgcn_global_load_lds(
        (const __attribute__((address_space(1))) void*)g,
        (__attribute__((address_space(3))) void*)l, 16, 0, 0);
}
__device__ __forceinline__ ull shfl_xor_u64(ull x, int j) {
    unsigned lo = (unsigned)x, hi = (unsigned)(x >> 32);
    lo = __shfl_xor(lo, j); hi = __shfl_xor(hi, j);
    return ((ull)hi << 32) | lo;
}
// merge two ascending sorted-64 lists, keep smallest 64; optional re-sort.
__device__ __forceinline__ ull merge_discard(ull a, ull b, int lane, bool clean) {
    ull rev = shfl_xor_u64(b, 63);
    ull m = a < rev ? a : rev;
    if (clean) {
#pragma unroll
        for (int j = 32; j > 0; j >>= 1) {
            ull p = shfl_xor_u64(m, j);
            bool keep_lo = ((lane & j) == 0);
            bool alt = m < p;
            ull lo = alt ? m : p, hi = alt ? p : m;
            m = keep_lo ? lo : hi;
        }
    }
    return m;
}

// ---------------------------------------------------------------------------
// Prep kernel (pure converts): one launch.
// ---------------------------------------------------------------------------
__global__ __launch_bounds__(256) void mega_prep_k(
    const float* __restrict__ features,
    const float* __restrict__ Wd, const float* __restrict__ bd,
    const float* __restrict__ Wq, const float* __restrict__ Wk, const float* __restrict__ Wv,
    const float* __restrict__ Wo, const float* __restrict__ bo, const float* __restrict__ We,
    u16* __restrict__ Fb, u16* __restrict__ Wob, u16* __restrict__ W3)
{
    __shared__ float T[64][65];
    int bid = blockIdx.x, tid = threadIdx.x;

    if (bid < 768) {                       // ---- convF
        int i = (bid * 256 + tid) * 4;
        float4 v = *(const float4*)&features[i];
        uint2 o;
        o.x = f2bf(v.x) | (f2bf(v.y) << 16);
        o.y = f2bf(v.z) | (f2bf(v.w) << 16);
        *(uint2*)&Fb[i] = o;
        return;
    }
    if (bid < 816) {                       // ---- extra A rows
        int flat = (bid - 768) * 1024 + tid * 4;   // 64x768 region
        int r = flat / DIM, c = flat - r * DIM;
        uint2 o; o.x = 0u; o.y = 0u;
        if (r == 0) {
            float4 v = *(const float4*)&Wd[c];
            o.x = f2bf(v.x) | (f2bf(v.y) << 16);
            o.y = f2bf(v.z) | (f2bf(v.w) << 16);
        } else if (r == 1) {
            float4 v = *(const float4*)&bd[c];
            o.x = f2bf(v.x) | (f2bf(v.y) << 16);
            o.y = f2bf(v.z) | (f2bf(v.w) << 16);
        }
        *(uint2*)&Fb[(size_t)(MROWS + r) * DIM + c] = o;
        return;
    }
    if (bid < 1440) {                      // ---- Wob = [Wo; bo; zeros]
        int flat = (bid - 816) * 1024 + tid * 4;   // 832x768 region
        int r = flat / DIM, c = flat - r * DIM;
        uint2 o; o.x = 0u; o.y = 0u;
        if (r < DIM) {
            float4 v = *(const float4*)&Wo[(size_t)r * DIM + c];
            o.x = f2bf(v.x) | (f2bf(v.y) << 16);
            o.y = f2bf(v.z) | (f2bf(v.w) << 16);
        } else if (r == DIM) {
            float4 v = *(const float4*)&bo[c];
            o.x = f2bf(v.x) | (f2bf(v.y) << 16);
            o.y = f2bf(v.z) | (f2bf(v.w) << 16);
        }
        *(uint2*)&Wob[(size_t)r * DIM + c] = o;
        return;
    }
    // ---- convT: 5 matrices x 144 (12x12) tile-blocks
    {
        int t = bid - 1440;
        int m = t / 144, r2 = t % 144;
        int by = r2 / 12, bx = r2 % 12;
        const float* S = (m == 0) ? Wq : (m == 1) ? Wk : (m == 2) ? Wv
                       : (m == 3) ? We : (We + WSQ);
        u16* D = W3 + (size_t)m * WSQ;
        int r0 = by * 64, c0 = bx * 64;
#pragma unroll
        for (int i = 0; i < 16; ++i) {
            int lin = tid + i * 256;
            int r = lin >> 6, c = lin & 63;
            T[r][c] = S[(size_t)(r0 + r) * DIM + c0 + c];
        }
        __syncthreads();
#pragma unroll
        for (int i = 0; i < 16; ++i) {
            int lin = tid + i * 256;
            int c = lin >> 6, r = lin & 63;
            D[(size_t)(c0 + c) * DIM + r0 + r] = (u16)f2bf(T[r][c]);
        }
    }
}

// ---------------------------------------------------------------------------
// Combined topk + QKV/Weff/Z0 GEMM launch.
//  bid < 256   : topk — one wave per point, in-register partial select
//  [256,1072)  : GEMM z = (bid-256)/204 (z0:FQ z1:FKb z2:FVb z3:WeffT+c_e)
//  [1072,1264) : GEMM z4: Z0 = Fb @ WeTopT + be
// GEMM: 64x64 tile, BK=64, global_load_lds w16 into LINEAR LDS with
// source-XOR swizzle (c ^= row&7); ds_read applies the same XOR.
// ---------------------------------------------------------------------------
union alignas(16) GTSm {
    struct { short As[64 * 64]; short Bs[64 * 64]; } g;   // 16384 B
    float P[NPTS * 3];                                    // 6144 B
};

__global__ __launch_bounds__(256) void qkvw_topk_k(
    const u16* __restrict__ Fb, const u16* __restrict__ Wob, const u16* __restrict__ W3,
    const float* __restrict__ bq, const float* __restrict__ be,
    const float* __restrict__ pts,
    float* __restrict__ FQ, u16* __restrict__ FKb, u16* __restrict__ FVb,
    u16* __restrict__ WeffT, float* __restrict__ c_e, float* __restrict__ Z0,
    int* __restrict__ idxb, float* __restrict__ distb)
{
    __shared__ GTSm sm;
    int bid = blockIdx.x, tid = threadIdx.x;
    int wv = tid >> 6, lane = tid & 63;

    if (bid < 256) {                       // ================= topk =================
        int bn = bid * 4 + wv;             // one wave per point
        int b  = bn >> 9;
        int n  = bn & (NPTS - 1);
        const float* pb = pts + (size_t)b * NPTS * 3;
        for (int i = tid; i < NPTS * 3; i += 256) sm.P[i] = pb[i];
        __syncthreads();

        float xn = sm.P[n * 3], yn = sm.P[n * 3 + 1], zn = sm.P[n * 3 + 2];
        float sqn = xn * xn + yn * yn + zn * zn;
        ull key[8];
#pragma unroll
        for (int r = 0; r < 8; ++r) {
            int m = r * 64 + lane;
            float xm = sm.P[m * 3], ym = sm.P[m * 3 + 1], zm = sm.P[m * 3 + 2];
            float d2 = sqn + (xm * xm + ym * ym + zm * zm)
                     - 2.0f * (xn * xm + yn * ym + zn * zm);
            unsigned db = __float_as_uint(fmaxf(d2, 0.0f));
            key[r] = ((ull)db << 32) | (unsigned)m;
        }

        // sort each register's 64-list ascending (21 stages)
#pragma unroll
        for (int k = 2; k <= 64; k <<= 1) {
#pragma unroll
            for (int j = k >> 1; j > 0; j >>= 1) {
#pragma unroll
                for (int r = 0; r < 8; ++r) {
                    ull p = shfl_xor_u64(key[r], j);
                    bool up = ((lane & k) == 0);
                    bool keep_lo = up == ((lane & j) == 0);
                    bool alt = key[r] < p;
                    ull lo = alt ? key[r] : p, hi = alt ? p : key[r];
                    key[r] = keep_lo ? lo : hi;
                }
            }
        }

        // merge-discard tree 8 -> 4 -> 2 -> 1
        key[0] = merge_discard(key[0], key[4], lane, true);
        key[1] = merge_discard(key[1], key[5], lane, true);
        key[2] = merge_discard(key[2], key[6], lane, true);
        key[3] = merge_discard(key[3], key[7], lane, true);
        key[0] = merge_discard(key[0], key[2], lane, true);
        key[1] = merge_discard(key[1], key[3], lane, true);
        key[0] = merge_discard(key[0], key[1], lane, false);

        ull k0 = key[0];
        idxb[(size_t)bn * KNN + lane]  = (int)(k0 & 0xffffffffu);
        distb[(size_t)bn * KNN + lane] = sqrtf(__uint_as_float((unsigned)(k0 >> 32)));
        return;
    }

    // ================= GEMM =================
    int bid2 = bid - 256;
    int z, by, bx;
    if (bid2 < 816) {
        z = bid2 / 204;
        int rem = bid2 - z * 204;
        by = rem / 12; bx = rem - by * 12;
        if (z == 0 && by >= 16) return;
        if (z == 3 && by >= 13) return;
    } else {
        z = 4;
        int rem = bid2 - 816;
        by = rem / 12; bx = rem - by * 12;
    }
    const u16* A  = (z == 3) ? Wob : Fb;
    const u16* BT = W3 + (size_t)((z == 3) ? 4 : (z == 4) ? 3 : z) * WSQ;

    int wr = (wv >> 1) * 32, wc = (wv & 1) * 32;
    int l15 = lane & 15, kg = lane >> 4;
    int brow = by * 64, bcol = bx * 64;

    f32x4 acc[2][2] = {};

    // staging decomposition: flat = i*256+tid, row = flat>>3, c = flat&7
    int srow = tid >> 3;            // row for i=0 (rows 0..31); i=1 -> +32
    int sc0  = tid & 7;

    for (int k0 = 0; k0 < DIM; k0 += 64) {
#pragma unroll
        for (int i = 0; i < 2; ++i) {
            int row = srow + i * 32;
            int cs = sc0 ^ (row & 7);
            gload_lds16(&A[(size_t)(brow + row) * DIM + k0 + cs * 8],
                        &sm.g.As[(i * 256 + wv * 64) * 8]);
            gload_lds16(&BT[(size_t)(bcol + row) * DIM + k0 + cs * 8],
                        &sm.g.Bs[(i * 256 + wv * 64) * 8]);
        }
        __syncthreads();
#pragma unroll
        for (int kk = 0; kk < 2; ++kk) {
            int r0 = wr + l15, r1 = wr + 16 + l15;
            int c0 = wc + l15, c1 = wc + 16 + l15;
            short8 a0 = *(const short8*)&sm.g.As[r0 * 64 + ((kk * 4 + kg) ^ (r0 & 7)) * 8];
            short8 a1 = *(const short8*)&sm.g.As[r1 * 64 + ((kk * 4 + kg) ^ (r1 & 7)) * 8];
            short8 b0 = *(const short8*)&sm.g.Bs[c0 * 64 + ((kk * 4 + kg) ^ (c0 & 7)) * 8];
            short8 b1 = *(const short8*)&sm.g.Bs[c1 * 64 + ((kk * 4 + kg) ^ (c1 & 7)) * 8];
            acc[0][0] = __builtin_amdgcn_mfma_f32_16x16x32_bf16(a0, b0, acc[0][0], 0, 0, 0);
            acc[0][1] = __builtin_amdgcn_mfma_f32_16x16x32_bf16(a0, b1, acc[0][1], 0, 0, 0);
            acc[1][0] = __builtin_amdgcn_mfma_f32_16x16x32_bf16(a1, b0, acc[1][0], 0, 0, 0);
            acc[1][1] = __builtin_amdgcn_mfma_f32_16x16x32_bf16(a1, b1, acc[1][1], 0, 0, 0);
        }
        __syncthreads();
    }

    // D layout: col = lane&15, row = (lane>>4)*4 + j
#pragma unroll
    for (int m = 0; m < 2; ++m) {
#pragma unroll
        for (int n = 0; n < 2; ++n) {
            int col  = bcol + wc + n * 16 + l15;
            int row0 = brow + wr + m * 16 + kg * 4;
            if (z == 0) {
                float bv = bq[col];
#pragma unroll
                for (int j = 0; j < 4; ++j)
                    FQ[(size_t)(row0 + j) * DIM + col] = acc[m][n][j] + bv;
            } else if (z == 1) {
#pragma unroll
                for (int j = 0; j < 4; ++j)
                    FKb[(size_t)(row0 + j) * DIM + col] = (u16)f2bf(acc[m][n][j]);
            } else if (z == 2) {
#pragma unroll
                for (int j = 0; j < 4; ++j)
                    FVb[(size_t)(row0 + j) * DIM + col] = (u16)f2bf(acc[m][n][j]);
            } else if (z == 4) {
                float bv = be[col];
#pragma unroll
                for (int j = 0; j < 4; ++j)
                    Z0[(size_t)(row0 + j) * DIM + col] = acc[m][n][j] + bv;
            } else {
                if (row0 + 3 < DIM) {
                    ull pk =
                          (ull)f2bf(acc[m][n][0])
                        | ((ull)f2bf(acc[m][n][1]) << 16)
                        | ((ull)f2bf(acc[m][n][2]) << 32)
                        | ((ull)f2bf(acc[m][n][3]) << 48);
                    *(ull*)&WeffT[(size_t)col * DIM + row0] = pk;
                } else {
#pragma unroll
                    for (int j = 0; j < 4; ++j) {
                        int row = row0 + j;
                        if (row < DIM)       WeffT[(size_t)col * DIM + row] = (u16)f2bf(acc[m][n][j]);
                        else if (row == DIM) c_e[col] = acc[m][n][j];
                    }
                }
            }
        }
    }
}

// ---------------------------------------------------------------------------
// Final GEMM: Z1 = Ob @ WeffT + c_e  (same gld_lds structure)
// ---------------------------------------------------------------------------
__global__ __launch_bounds__(256) void gemm_z1_k(
    const u16* __restrict__ Ob, const u16* __restrict__ WeffT,
    const float* __restrict__ c_e, float* __restrict__ Z1)
{
    __shared__ short As[64 * 64];
    __shared__ short Bs[64 * 64];

    int tid  = threadIdx.x;
    int wv = tid >> 6, lane = tid & 63;
    int wr = (wv >> 1) * 32, wc = (wv & 1) * 32;
    int l15 = lane & 15, kg = lane >> 4;
    int brow = blockIdx.y * 64, bcol = blockIdx.x * 64;

    f32x4 acc[2][2] = {};

    int srow = tid >> 3;
    int sc0  = tid & 7;

    for (int k0 = 0; k0 < DIM; k0 += 64) {
#pragma unroll
        for (int i = 0; i < 2; ++i) {
            int row = srow + i * 32;
            int cs = sc0 ^ (row & 7);
            gload_lds16(&Ob[(size_t)(brow + row) * DIM + k0 + cs * 8],
                        &As[(i * 256 + wv * 64) * 8]);
            gload_lds16(&WeffT[(size_t)(bcol + row) * DIM + k0 + cs * 8],
                        &Bs[(i * 256 + wv * 64) * 8]);
        }
        __syncthreads();
#pragma unroll
        for (int kk = 0; kk < 2; ++kk) {
            int r0 = wr + l15, r1 = wr + 16 + l15;
            int c0 = wc + l15, c1 = wc + 16 + l15;
            short8 a0 = *(const short8*)&As[r0 * 64 + ((kk * 4 + kg) ^ (r0 & 7)) * 8];
            short8 a1 = *(const short8*)&As[r1 * 64 + ((kk * 4 + kg) ^ (r1 & 7)) * 8];
            short8 b0 = *(const short8*)&Bs[c0 * 64 + ((kk * 4 + kg) ^ (c0 & 7)) * 8];
            short8 b1 = *(const short8*)&Bs[c1 * 64 + ((kk * 4 + kg) ^ (c1 & 7)) * 8];
            acc[0][0] = __builtin_amdgcn_mfma_f32_16x16x32_bf16(a0, b0, acc[0][0], 0, 0, 0);
            acc[0][1] = __builtin_amdgcn_mfma_f32_16x16x32_bf16(a0, b1, acc[0][1], 0, 0, 0);
            acc[1][0] = __builtin_amdgcn_mfma_f32_16x16x32_bf16(a1, b0, acc[1][0], 0, 0, 0);
            acc[1][1] = __builtin_amdgcn_mfma_f32_16x16x32_bf16(a1, b1, acc[1][1], 0, 0, 0);
        }
        __syncthreads();
    }

#pragma unroll
    for (int m = 0; m < 2; ++m) {
#pragma unroll
        for (int n = 0; n < 2; ++n) {
            int col = bcol + wc + n * 16 + l15;
            float bv = c_e[col];
#pragma unroll
            for (int j = 0; j < 4; ++j) {
                int row = brow + wr + m * 16 + kg * 4 + j;
                Z1[(size_t)row * DIM + col] = acc[m][n][j] + bv;
            }
        }
    }
}

// ---------------------------------------------------------------------------
// Fused neighbor attention, shuffle-free score phase. 512 threads/block.
// ---------------------------------------------------------------------------
__global__ __launch_bounds__(512) void attn_k(
    const float* __restrict__ FQ, const u16* __restrict__ FKb, const u16* __restrict__ FVb,
    const int* __restrict__ idxb, const float* __restrict__ distb,
    const float* __restrict__ bk, const float* __restrict__ bv,
    u16* __restrict__ O)
{
    int bn = blockIdx.x;
    int b  = bn >> 9;
    int tid = threadIdx.x;
    int wv = tid >> 6, lane = tid & 63;

    __shared__ float qlds[NH][104];
    __shared__ int   s_idx[KNN];
    __shared__ float s_dist[KNN];
    __shared__ float s_sc[NH][68];
    __shared__ float s_att[NH][68];
    __shared__ float s_qh[NH][2];
    __shared__ float s_sd[NH];

    if (tid < KNN) {
        s_idx[tid]  = idxb[(size_t)bn * KNN + tid];
        s_dist[tid] = distb[(size_t)bn * KNN + tid];
    }
    const float* qrow = FQ + (size_t)bn * DIM;
    {
        int d = tid;
        if (d < DIM) qlds[d / HDIM][d % HDIM] = qrow[d];
        int d2 = tid + 512;
        if (d2 < DIM) qlds[d2 / HDIM][d2 % HDIM] = qrow[d2];
    }
    __syncthreads();

    {
        int h = wv;
        const u16* wdk = FKb + (size_t)MROWS * DIM + h * HDIM;
        const u16* ckr = FKb + (size_t)(MROWS + 1) * DIM + h * HDIM;
        const float* bkh = bk + h * HDIM;
        float q = qlds[h][lane];
        float pw = q * bf2f(wdk[lane]);
        float pc = q * (bf2f(ckr[lane]) + bkh[lane]);
        if (lane < HDIM - 64) {
            float q2 = qlds[h][lane + 64];
            pw = fmaf(q2, bf2f(wdk[lane + 64]), pw);
            pc = fmaf(q2, bf2f(ckr[lane + 64]) + bkh[lane + 64], pc);
        }
#pragma unroll
        for (int off = 32; off; off >>= 1) {
            pw += __shfl_xor(pw, off);
            pc += __shfl_xor(pc, off);
        }
        if (lane == 0) { s_qh[h][0] = pw; s_qh[h][1] = pc; }
    }

    {
        int j = tid >> 3, h = tid & 7;
        const u16* kr = FKb + (size_t)(b * NPTS + s_idx[j]) * DIM + h * HDIM;
        const uint4* kr4 = (const uint4*)kr;
        float a0 = 0.f, a1 = 0.f, a2 = 0.f, a3 = 0.f;
#pragma unroll
        for (int i = 0; i < 12; ++i) {
            uint4 kv = kr4[i];
            float4 qa = *(const float4*)&qlds[h][i * 8];
            float4 qb = *(const float4*)&qlds[h][i * 8 + 4];
            a0 = fmaf(qa.x, __uint_as_float(kv.x << 16), a0);
            a1 = fmaf(qa.y, __uint_as_float(kv.x & 0xffff0000u), a1);
            a2 = fmaf(qa.z, __uint_as_float(kv.y << 16), a2);
            a3 = fmaf(qa.w, __uint_as_float(kv.y & 0xffff0000u), a3);
            a0 = fmaf(qb.x, __uint_as_float(kv.z << 16), a0);
            a1 = fmaf(qb.y, __uint_as_float(kv.z & 0xffff0000u), a1);
            a2 = fmaf(qb.z, __uint_as_float(kv.w << 16), a2);
            a3 = fmaf(qb.w, __uint_as_float(kv.w & 0xffff0000u), a3);
        }
        s_sc[h][j] = (a0 + a1) + (a2 + a3);
    }
    __syncthreads();

    {
        int h = wv, j = lane;
        const float invs = 0.10206207261596575f;
        float qwdk = s_qh[h][0], qck = s_qh[h][1];
        float dj = s_dist[j];
        float sc = (s_sc[h][j] + dj * qwdk + qck) * invs;
        float mx = sc;
#pragma unroll
        for (int off = 32; off; off >>= 1) mx = fmaxf(mx, __shfl_xor(mx, off));
        float ev = __expf(sc - mx);
        float sum = ev;
#pragma unroll
        for (int off = 32; off; off >>= 1) sum += __shfl_xor(sum, off);
        float att = ev / sum;
        s_att[h][j] = att;
        float sd = att * dj;
#pragma unroll
        for (int off = 32; off; off >>= 1) sd += __shfl_xor(sd, off);
        if (lane == 0) s_sd[h] = sd;
    }
    __syncthreads();

    if (tid < 384) {
        int d0 = tid * 2;
        int h  = d0 / HDIM;
        const float* attp = s_att[h];
        const size_t basev = (size_t)(b * NPTS) * DIM + d0;
        float o0 = 0.f, o1 = 0.f;
#pragma unroll 4
        for (int j = 0; j < KNN; ++j) {
            unsigned pv = *(const unsigned*)&FVb[basev + (size_t)s_idx[j] * DIM];
            float a = attp[j];
            o0 = fmaf(a, __uint_as_float(pv << 16), o0);
            o1 = fmaf(a, __uint_as_float(pv & 0xffff0000u), o1);
        }
        const u16* wdv = FVb + (size_t)MROWS * DIM;
        const u16* cvr = FVb + (size_t)(MROWS + 1) * DIM;
        float sdh = s_sd[h];
        o0 += sdh * bf2f(wdv[d0])     + (bf2f(cvr[d0])     + bv[d0]);
        o1 += sdh * bf2f(wdv[d0 + 1]) + (bf2f(cvr[d0 + 1]) + bv[d0 + 1]);
        unsigned po = f2bf(o0) | (f2bf(o1) << 16);
        *(unsigned*)&O[(size_t)bn * DIM + d0] = po;
    }
}

// ---------------------------------------------------------------------------
// LayerNorm + SiLU; x = Z0 + Z1. 192 threads, float4/thread.
// ---------------------------------------------------------------------------
__global__ __launch_bounds__(192) void ln_silu_k(
    const float* __restrict__ Z0, const float* __restrict__ Z1,
    const float* __restrict__ g, const float* __restrict__ bta,
    float* __restrict__ out)
{
    int bn = blockIdx.x, tid = threadIdx.x;
    size_t ro = (size_t)bn * DIM;
    int e0 = tid * 4;
    float4 x = *(const float4*)&Z0[ro + e0];
    {
        float4 p = *(const float4*)&Z1[ro + e0];
        x.x += p.x; x.y += p.y; x.z += p.z; x.w += p.w;
    }
    float s  = (x.x + x.y) + (x.z + x.w);
    float ss = (x.x * x.x + x.y * x.y) + (x.z * x.z + x.w * x.w);
    __shared__ float red[3][2];
#pragma unroll
    for (int off = 32; off; off >>= 1) {
        s  += __shfl_xor(s, off);
        ss += __shfl_xor(ss, off);
    }
    int w = tid >> 6;
    if ((tid & 63) == 0) { red[w][0] = s; red[w][1] = ss; }
    __syncthreads();
    s  = red[0][0] + red[1][0] + red[2][0];
    ss = red[0][1] + red[1][1] + red[2][1];
    float mean = s * (1.0f / DIM);
    float var  = ss * (1.0f / DIM) - mean * mean;
    float rstd = rsqrtf(var + 1e-5f);
    float4 gv = *(const float4*)&g[e0];
    float4 bv = *(const float4*)&bta[e0];
    float4 y;
    y.x = (x.x - mean) * rstd * gv.x + bv.x;
    y.y = (x.y - mean) * rstd * gv.y + bv.y;
    y.z = (x.z - mean) * rstd * gv.z + bv.z;
    y.w = (x.w - mean) * rstd * gv.w + bv.w;
    float4 o;
    o.x = y.x / (1.0f + __expf(-y.x));
    o.y = y.y / (1.0f + __expf(-y.y));
    o.z = y.z / (1.0f + __expf(-y.z));
    o.w = y.w / (1.0f + __expf(-y.w));
    *(float4*)&out[ro + e0] = o;
}

// ---------------------------------------------------------------------------
extern "C" void kernel_launch(void* const* d_in, const int* in_sizes, int n_in,
                              void* d_out, int out_size, void* d_ws, size_t ws_size,
                              hipStream_t stream)
{
    const float* features = (const float*)d_in[0];
    const float* pts      = (const float*)d_in[1];
    const float* Wd       = (const float*)d_in[2];
    const float* bd       = (const float*)d_in[3];
    const float* Wq       = (const float*)d_in[4];
    const float* bq       = (const float*)d_in[5];
    const float* Wk       = (const float*)d_in[6];
    const float* bk       = (const float*)d_in[7];
    const float* Wv       = (const float*)d_in[8];
    const float* bv       = (const float*)d_in[9];
    const float* Wo       = (const float*)d_in[10];
    const float* bo       = (const float*)d_in[11];
    const float* We       = (const float*)d_in[12];
    const float* be       = (const float*)d_in[13];
    const float* g_ln     = (const float*)d_in[14];
    const float* b_ln     = (const float*)d_in[15];

    const size_t MAT  = (size_t)MROWS * DIM;   // 786432
    const size_t MATP = (size_t)MPAD  * DIM;   // 835584

    float* ws = (float*)d_ws;
    float* FQ    = ws;                       // [1088][768] f32
    u16*   FKb   = (u16*)(ws + MATP);        // [1088][768] bf16 (rows 1024/1025 = wdk/ck)
    u16*   FVb   = FKb + MATP;               // [1088][768] bf16
    u16*   Fb    = FVb + MATP;               // [1088][768] bf16 (features + Wd/bd rows)
    u16*   Ob    = Fb + MATP;                // [1024][768] bf16 (attention output)
    u16*   Wob   = Ob + MAT;                 // [832][768] bf16 ([Wo; bo; 0])
    u16*   W3    = Wob + (size_t)WOROWS * DIM;  // 5 x [768][768] bf16 transposed
    u16*   WeffT = W3 + 5 * WSQ;             // [768][768] bf16 (Wo@WeBot)^T
    float* c_e   = (float*)(WeffT + WSQ);    // [768] f32 (bo@WeBot)
    int*   idxb  = (int*)(c_e + DIM);
    float* distb = (float*)(idxb + (size_t)MROWS * KNN);
    float* Z0    = distb + (size_t)MROWS * KNN;   // [1024][768] f32
    float* Z1    = Z0 + MAT;                      // [1024][768] f32

    // 1) pure-convert prep
    mega_prep_k<<<2160, 256, 0, stream>>>(features, Wd, bd, Wq, Wk, Wv, Wo, bo, We,
                                          Fb, Wob, W3);
    // 2) topk + QKV/Weff/Z0 GEMMs (gld_lds w16, swizzled), one launch
    qkvw_topk_k<<<1264, 256, 0, stream>>>(
        Fb, Wob, W3, bq, be, pts, FQ, FKb, FVb, WeffT, c_e, Z0, idxb, distb);
    // 3) fused neighbor attention
    attn_k<<<MROWS, 512, 0, stream>>>(FQ, FKb, FVb, idxb, distb, bk, bv, Ob);
    // 4) Z1 = Ob @ WeffT + c_e
    gemm_z1_k<<<dim3(12, 16), 256, 0, stream>>>(Ob, WeffT, c_e, Z1);
    // 5) LayerNorm(Z0 + Z1) + SiLU
    ln_silu_k<<<MROWS, 192, 0, stream>>>(Z0, Z1, g_ln, b_ln, (float*)d_out);
}